// Round 5
// baseline (32.375 us; speedup 1.0000x reference)
//
#include <hip/hip_runtime.h>

// PyQHamiltonianEvolution: N_QUBITS=20, SUPPORT=(3,8,15), BATCH=8, DIM=8
// state layout (2,)*20 + (8,) row-major, batch innermost.
// element-address support bits: q3 -> bit19 (524288), q8 -> bit14 (16384),
// q15 -> bit7 (128); batch = bits 0-2. Output = f32 REAL part, 2^23 elems.
//
// Kernel A: U[b] = expm(-i t_b H), f32 scaling-squaring (s=5, K=10), one
//           block, result to d_ws as float2 U2[(o*8+i)*8 + b].
// Kernel B: thread owns one batch-OCTET (rest index rho, all 8 batches).
//           All lanes need identical U values -> wave-uniform -> s_load into
//           SGPRs (scalar pipe), zero LDS. 8 gathers x 2 planes x 2 float4
//           loads; 8x8 complex matvec real part; 16 float4 stores.

#define SUP_OFF(m) ( ((m)&4 ? 524288u : 0u) + ((m)&2 ? 16384u : 0u) + ((m)&1 ? 128u : 0u) )

__global__ void expm_kernel(const float* __restrict__ h_real,
                            const float* __restrict__ h_imag,
                            const float* __restrict__ t_g,
                            float2* __restrict__ U2)
{
    __shared__ float Tre[8][64], Tim[8][64];
    __shared__ float Mre[8][64], Mim[8][64];
    __shared__ float Ere[8][64], Eim[8][64];

    const int tid = threadIdx.x;          // 0..255
    const int b   = tid >> 5;             // batch
    const int e0  = tid & 31;             // entries e0 and e0+32
    const int e1  = e0 + 32;
    const int o0 = e0 >> 3, i0 = e0 & 7;
    const int o1 = e1 >> 3, i1 = e1 & 7;

    const float sc   = t_g[b] * (1.0f / 32.0f);   // M = (-i t H) / 2^5
    const float m0re =  sc * h_imag[e0];
    const float m0im = -sc * h_real[e0];
    const float m1re =  sc * h_imag[e1];
    const float m1im = -sc * h_real[e1];

    Mre[b][e0] = m0re; Mim[b][e0] = m0im;
    Mre[b][e1] = m1re; Mim[b][e1] = m1im;
    Tre[b][e0] = m0re; Tim[b][e0] = m0im;
    Tre[b][e1] = m1re; Tim[b][e1] = m1im;
    float a0re = (o0 == i0 ? 1.f : 0.f) + m0re, a0im = m0im;   // E = I + M
    float a1re = (o1 == i1 ? 1.f : 0.f) + m1re, a1im = m1im;
    __syncthreads();

    for (int k = 2; k <= 10; ++k) {       // T = T*M/k ; E += T
        float s0re = 0.f, s0im = 0.f, s1re = 0.f, s1im = 0.f;
        #pragma unroll
        for (int j = 0; j < 8; ++j) {
            float tre = Tre[b][o0 * 8 + j], tim = Tim[b][o0 * 8 + j];
            float mre = Mre[b][j * 8 + i0], mim = Mim[b][j * 8 + i0];
            s0re += tre * mre - tim * mim;
            s0im += tre * mim + tim * mre;
            tre = Tre[b][o1 * 8 + j]; tim = Tim[b][o1 * 8 + j];
            mre = Mre[b][j * 8 + i1]; mim = Mim[b][j * 8 + i1];
            s1re += tre * mre - tim * mim;
            s1im += tre * mim + tim * mre;
        }
        const float inv = 1.0f / (float)k;
        s0re *= inv; s0im *= inv; s1re *= inv; s1im *= inv;
        __syncthreads();
        Tre[b][e0] = s0re; Tim[b][e0] = s0im;
        Tre[b][e1] = s1re; Tim[b][e1] = s1im;
        a0re += s0re; a0im += s0im;
        a1re += s1re; a1im += s1im;
        __syncthreads();
    }

    Ere[b][e0] = a0re; Eim[b][e0] = a0im;
    Ere[b][e1] = a1re; Eim[b][e1] = a1im;
    __syncthreads();

    for (int sq = 0; sq < 5; ++sq) {      // E = E*E
        float s0re = 0.f, s0im = 0.f, s1re = 0.f, s1im = 0.f;
        #pragma unroll
        for (int j = 0; j < 8; ++j) {
            float xre = Ere[b][o0 * 8 + j], xim = Eim[b][o0 * 8 + j];
            float yre = Ere[b][j * 8 + i0], yim = Eim[b][j * 8 + i0];
            s0re += xre * yre - xim * yim;
            s0im += xre * yim + xim * yre;
            xre = Ere[b][o1 * 8 + j]; xim = Eim[b][o1 * 8 + j];
            yre = Ere[b][j * 8 + i1]; yim = Eim[b][j * 8 + i1];
            s1re += xre * yre - xim * yim;
            s1im += xre * yim + xim * yre;
        }
        __syncthreads();
        if (sq < 4) {
            Ere[b][e0] = s0re; Eim[b][e0] = s0im;
            Ere[b][e1] = s1re; Eim[b][e1] = s1im;
            __syncthreads();
        } else {
            U2[e0 * 8 + b] = make_float2(s0re, s0im);   // planar: [(o*8+i)*8+b]
            U2[e1 * 8 + b] = make_float2(s1re, s1im);
        }
    }
}

__global__ __launch_bounds__(256, 2) void apply_kernel(
        const float* __restrict__ sre_g,
        const float* __restrict__ sim_g,
        const float4* __restrict__ Uv,    // [(o*8+i)*4 + k]: k -> batch pair
        float* __restrict__ out)
{
    const int rho = blockIdx.x * 256 + threadIdx.x;   // [0, 2^17) rest index

    // spread rho's 17 bits into octet-addr bits, skipping support bits 4,11,16
    const unsigned oct = (rho & 0xFu)
                       | ((rho & 0x3F0u)   << 1)
                       | ((rho & 0x3C00u)  << 2)
                       | ((rho & 0x1C000u) << 3);
    const unsigned base = oct << 3;       // element address of octet start

    // gather: 8 support combos x {re,im} x 2 float4 (batches 0-3, 4-7)
    float4 xr0[8], xr1[8], xi0[8], xi1[8];
    #pragma unroll
    for (int i = 0; i < 8; ++i) {
        const unsigned off = base + SUP_OFF(i);
        xr0[i] = *(const float4*)(sre_g + off);
        xr1[i] = *(const float4*)(sre_g + off + 4);
        xi0[i] = *(const float4*)(sim_g + off);
        xi1[i] = *(const float4*)(sim_g + off + 4);
    }

    for (int o = 0; o < 8; ++o) {
        float4 a0 = make_float4(0.f, 0.f, 0.f, 0.f);
        float4 a1 = make_float4(0.f, 0.f, 0.f, 0.f);
        #pragma unroll
        for (int i = 0; i < 8; ++i) {
            // wave-uniform addresses -> scalar loads into SGPRs
            const float4 u01 = Uv[(o * 8 + i) * 4 + 0];  // (re0,im0,re1,im1)
            const float4 u23 = Uv[(o * 8 + i) * 4 + 1];
            const float4 u45 = Uv[(o * 8 + i) * 4 + 2];
            const float4 u67 = Uv[(o * 8 + i) * 4 + 3];
            a0.x += u01.x * xr0[i].x - u01.y * xi0[i].x;
            a0.y += u01.z * xr0[i].y - u01.w * xi0[i].y;
            a0.z += u23.x * xr0[i].z - u23.y * xi0[i].z;
            a0.w += u23.z * xr0[i].w - u23.w * xi0[i].w;
            a1.x += u45.x * xr1[i].x - u45.y * xi1[i].x;
            a1.y += u45.z * xr1[i].y - u45.w * xi1[i].y;
            a1.z += u67.x * xr1[i].z - u67.y * xi1[i].z;
            a1.w += u67.z * xr1[i].w - u67.w * xi1[i].w;
        }
        const unsigned off = base + SUP_OFF(o);
        *(float4*)(out + off)     = a0;
        *(float4*)(out + off + 4) = a1;
    }
}

extern "C" void kernel_launch(void* const* d_in, const int* in_sizes, int n_in,
                              void* d_out, int out_size, void* d_ws, size_t ws_size,
                              hipStream_t stream) {
    const float* state_real = (const float*)d_in[0];
    const float* state_imag = (const float*)d_in[1];
    const float* h_real     = (const float*)d_in[2];
    const float* h_imag     = (const float*)d_in[3];
    const float* t          = (const float*)d_in[4];

    float2* U2 = (float2*)d_ws;   // 512 complex = 4 KB

    expm_kernel<<<1, 256, 0, stream>>>(h_real, h_imag, t, U2);

    // 2^17 octets, one per thread
    apply_kernel<<<512, 256, 0, stream>>>(state_real, state_imag,
                                          (const float4*)U2, (float*)d_out);
}

// Round 6
// 29.574 us; speedup vs baseline: 1.0947x; 1.0947x over previous
//
#include <hip/hip_runtime.h>

// PyQHamiltonianEvolution: N_QUBITS=20, SUPPORT=(3,8,15), BATCH=8, DIM=8
// state layout (2,)*20 + (8,) row-major, batch innermost.
// element-address support bits: q3 -> bit19 (524288), q8 -> bit14 (16384),
// q15 -> bit7 (128); batch = bits 0-2. Output = f32 REAL part, 2^23 elems.
//
// Kernel A (1 block, ~1.5us): U[b] = expm(-i t_b H), f32 scaling-squaring
//           (s=5, K=10) -> d_ws as float2 U2[b*64 + o*8 + i].
// Kernel B (round-3 proven shape): one (rest x batch) element per thread,
//           U from LDS (8-distinct-address broadcast reads), gather 8 /
//           scatter 8, real part only, nontemporal stores, XCD swizzle.

#define SUP_OFF(m) ( ((m)&4 ? 524288u : 0u) + ((m)&2 ? 16384u : 0u) + ((m)&1 ? 128u : 0u) )

__global__ void expm_kernel(const float* __restrict__ h_real,
                            const float* __restrict__ h_imag,
                            const float* __restrict__ t_g,
                            float2* __restrict__ U2)
{
    __shared__ float Tre[8][64], Tim[8][64];
    __shared__ float Mre[8][64], Mim[8][64];
    __shared__ float Ere[8][64], Eim[8][64];

    const int tid = threadIdx.x;          // 0..255
    const int b   = tid >> 5;             // batch
    const int e0  = tid & 31;             // entries e0 and e0+32
    const int e1  = e0 + 32;
    const int o0 = e0 >> 3, i0 = e0 & 7;
    const int o1 = e1 >> 3, i1 = e1 & 7;

    const float sc   = t_g[b] * (1.0f / 32.0f);   // M = (-i t H) / 2^5
    const float m0re =  sc * h_imag[e0];
    const float m0im = -sc * h_real[e0];
    const float m1re =  sc * h_imag[e1];
    const float m1im = -sc * h_real[e1];

    Mre[b][e0] = m0re; Mim[b][e0] = m0im;
    Mre[b][e1] = m1re; Mim[b][e1] = m1im;
    Tre[b][e0] = m0re; Tim[b][e0] = m0im;
    Tre[b][e1] = m1re; Tim[b][e1] = m1im;
    float a0re = (o0 == i0 ? 1.f : 0.f) + m0re, a0im = m0im;   // E = I + M
    float a1re = (o1 == i1 ? 1.f : 0.f) + m1re, a1im = m1im;
    __syncthreads();

    for (int k = 2; k <= 10; ++k) {       // T = T*M/k ; E += T
        float s0re = 0.f, s0im = 0.f, s1re = 0.f, s1im = 0.f;
        #pragma unroll
        for (int j = 0; j < 8; ++j) {
            float tre = Tre[b][o0 * 8 + j], tim = Tim[b][o0 * 8 + j];
            float mre = Mre[b][j * 8 + i0], mim = Mim[b][j * 8 + i0];
            s0re += tre * mre - tim * mim;
            s0im += tre * mim + tim * mre;
            tre = Tre[b][o1 * 8 + j]; tim = Tim[b][o1 * 8 + j];
            mre = Mre[b][j * 8 + i1]; mim = Mim[b][j * 8 + i1];
            s1re += tre * mre - tim * mim;
            s1im += tre * mim + tim * mre;
        }
        const float inv = 1.0f / (float)k;
        s0re *= inv; s0im *= inv; s1re *= inv; s1im *= inv;
        __syncthreads();
        Tre[b][e0] = s0re; Tim[b][e0] = s0im;
        Tre[b][e1] = s1re; Tim[b][e1] = s1im;
        a0re += s0re; a0im += s0im;
        a1re += s1re; a1im += s1im;
        __syncthreads();
    }

    Ere[b][e0] = a0re; Eim[b][e0] = a0im;
    Ere[b][e1] = a1re; Eim[b][e1] = a1im;
    __syncthreads();

    for (int sq = 0; sq < 5; ++sq) {      // E = E*E
        float s0re = 0.f, s0im = 0.f, s1re = 0.f, s1im = 0.f;
        #pragma unroll
        for (int j = 0; j < 8; ++j) {
            float xre = Ere[b][o0 * 8 + j], xim = Eim[b][o0 * 8 + j];
            float yre = Ere[b][j * 8 + i0], yim = Eim[b][j * 8 + i0];
            s0re += xre * yre - xim * yim;
            s0im += xre * yim + xim * yre;
            xre = Ere[b][o1 * 8 + j]; xim = Eim[b][o1 * 8 + j];
            yre = Ere[b][j * 8 + i1]; yim = Eim[b][j * 8 + i1];
            s1re += xre * yre - xim * yim;
            s1im += xre * yim + xim * yre;
        }
        __syncthreads();
        if (sq < 4) {
            Ere[b][e0] = s0re; Eim[b][e0] = s0im;
            Ere[b][e1] = s1re; Eim[b][e1] = s1im;
            __syncthreads();
        } else {
            U2[b * 64 + e0] = make_float2(s0re, s0im);   // [b][o][i]
            U2[b * 64 + e1] = make_float2(s1re, s1im);
        }
    }
}

__global__ __launch_bounds__(256) void apply_kernel(
        const float* __restrict__ sre_g,
        const float* __restrict__ sim_g,
        const float2* __restrict__ U2,
        float* __restrict__ out)
{
    // U staged in LDS: per-batch stride 66 float2 (16B-aligned float4 reads;
    // 8 distinct addresses per wave read -> broadcast groups, conflict-free).
    __shared__ alignas(16) float2 uLds[8 * 66];
    const int tid = threadIdx.x;
    for (int v = tid; v < 512; v += 256) {
        uLds[(v >> 6) * 66 + (v & 63)] = U2[v];
    }
    __syncthreads();

    // XCD-aware bijective swizzle: 4096 blocks, 8 XCDs, 512 blocks/XCD chunk.
    const int bid = ((blockIdx.x & 7) << 9) | (blockIdx.x >> 3);

    const int r = bid * 256 + tid;          // r in [0, 2^20)
    const int b = r & 7;

    // Spread r's bits around address bits {7, 14, 19} (the support strides).
    const unsigned addr = (r & 0x7Fu)
                        | ((r & 0x1F80u)  << 1)
                        | ((r & 0x1E000u) << 2)
                        | ((r & 0xE0000u) << 3);

    // Gather the 8 support combinations. i = (q3<<2)|(q8<<1)|q15.
    float xre[8], xim[8];
    #pragma unroll
    for (int i = 0; i < 8; ++i) {
        const unsigned off = addr + SUP_OFF(i);
        xre[i] = sre_g[off];
        xim[i] = sim_g[off];
    }

    const float4* urow = reinterpret_cast<const float4*>(uLds) + b * 33;

    #pragma unroll
    for (int o = 0; o < 8; ++o) {
        float are = 0.f;
        #pragma unroll
        for (int p = 0; p < 4; ++p) {
            const float4 u = urow[o * 4 + p];   // U[b][o][2p], U[b][o][2p+1]
            const int i0 = 2 * p, i1 = 2 * p + 1;
            are += u.x * xre[i0] - u.y * xim[i0];
            are += u.z * xre[i1] - u.w * xim[i1];
        }
        __builtin_nontemporal_store(are, out + addr + SUP_OFF(o));
    }
}

extern "C" void kernel_launch(void* const* d_in, const int* in_sizes, int n_in,
                              void* d_out, int out_size, void* d_ws, size_t ws_size,
                              hipStream_t stream) {
    const float* state_real = (const float*)d_in[0];
    const float* state_imag = (const float*)d_in[1];
    const float* h_real     = (const float*)d_in[2];
    const float* h_imag     = (const float*)d_in[3];
    const float* t          = (const float*)d_in[4];

    float2* U2 = (float2*)d_ws;   // 512 complex = 4 KB

    expm_kernel<<<1, 256, 0, stream>>>(h_real, h_imag, t, U2);

    apply_kernel<<<4096, 256, 0, stream>>>(state_real, state_imag, U2,
                                           (float*)d_out);
}

// Round 7
// 28.082 us; speedup vs baseline: 1.1529x; 1.0531x over previous
//
#include <hip/hip_runtime.h>

// PyQHamiltonianEvolution: N_QUBITS=20, SUPPORT=(3,8,15), BATCH=8, DIM=8
// state layout (2,)*20 + (8,) row-major, batch innermost.
// element-address support bits: q3 -> bit19 (524288), q8 -> bit14 (16384),
// q15 -> bit7 (128); batch = bits 0-2. Output = f32 REAL part, 2^23 elems.
//
// Kernel A: expm, 8 blocks x 64 threads (one wave per batch, one matrix
//           entry per lane; single-wave workgroup -> barriers ~free).
//           U stored to d_ws as float[1024]: [(i*8+b)*16 + 2o] = re, +1 = im.
// Kernel B: accumulate-over-i apply. Thread owns 4 SAME-BATCH elements
//           (r, r+256, r+512, r+768 within the block's 1024-r range).
//           Per input-combo i: one U column from LDS (4x ds_read_b128,
//           broadcast, conflict-free via stride-20 pad), 8 loads, 64 FMA.
//           LDS traffic: 8 b128/element (was 32). Real-part accumulators only.

#define SUP_OFF(m) ( ((m)&4 ? 524288u : 0u) + ((m)&2 ? 16384u : 0u) + ((m)&1 ? 128u : 0u) )

__global__ void expm_kernel(const float* __restrict__ h_real,
                            const float* __restrict__ h_imag,
                            const float* __restrict__ t_g,
                            float* __restrict__ U)     // [ (i*8+b)*16 + 2o (+1) ]
{
    __shared__ float Tre[64], Tim[64], Mre[64], Mim[64], Ere[64], Eim[64];

    const int b = blockIdx.x;          // batch
    const int e = threadIdx.x;         // matrix entry, one per lane
    const int o = e >> 3, i = e & 7;

    const float sc  = t_g[b] * (1.0f / 32.0f);   // M = (-i t H) / 2^5
    const float mre =  sc * h_imag[e];
    const float mim = -sc * h_real[e];

    Mre[e] = mre; Mim[e] = mim;
    Tre[e] = mre; Tim[e] = mim;
    float are = (o == i ? 1.f : 0.f) + mre;      // E = I + M
    float aim = mim;
    __syncthreads();

    for (int k = 2; k <= 10; ++k) {    // T = T*M/k ; E += T
        float sre = 0.f, sim = 0.f;
        #pragma unroll
        for (int j = 0; j < 8; ++j) {
            const float tre = Tre[o * 8 + j], tim = Tim[o * 8 + j];
            const float qre = Mre[j * 8 + i], qim = Mim[j * 8 + i];
            sre += tre * qre - tim * qim;
            sim += tre * qim + tim * qre;
        }
        const float inv = 1.0f / (float)k;
        sre *= inv; sim *= inv;
        __syncthreads();
        Tre[e] = sre; Tim[e] = sim;
        are += sre; aim += sim;
        __syncthreads();
    }

    Ere[e] = are; Eim[e] = aim;
    __syncthreads();

    for (int sq = 0; sq < 5; ++sq) {   // E = E*E
        float sre = 0.f, sim = 0.f;
        #pragma unroll
        for (int j = 0; j < 8; ++j) {
            const float xre = Ere[o * 8 + j], xim = Eim[o * 8 + j];
            const float yre = Ere[j * 8 + i], yim = Eim[j * 8 + i];
            sre += xre * yre - xim * yim;
            sim += xre * yim + xim * yre;
        }
        __syncthreads();
        if (sq < 4) {
            Ere[e] = sre; Eim[e] = sim;
            __syncthreads();
        } else {
            U[(i * 8 + b) * 16 + 2 * o]     = sre;   // column-major for apply
            U[(i * 8 + b) * 16 + 2 * o + 1] = sim;
        }
    }
}

__global__ __launch_bounds__(256, 4) void apply_kernel(
        const float* __restrict__ sre_g,
        const float* __restrict__ sim_g,
        const float4* __restrict__ U4,   // 256 float4 = [i][b][16 floats]
        float* __restrict__ out)
{
    // LDS: [i][b] slots, stride 20 floats (80B = 5x16B: b128-aligned; banks
    // b*20 mod 32 = {0,20,8,28,16,4,24,12} all distinct -> conflict-free
    // 8-address broadcast reads).
    __shared__ alignas(16) float uL[8 * 8 * 20];
    const int tid = threadIdx.x;
    {
        const float4 u = U4[tid];            // tid = (i*8+b)*4 + k
        const int ib = tid >> 2, k = tid & 3;
        *(float4*)&uL[ib * 20 + k * 4] = u;
    }
    __syncthreads();

    const unsigned rbase = blockIdx.x * 1024u + tid;   // block owns 1024 r
    const int b = tid & 7;                             // same b for all 4 sets

    unsigned addr[4];
    #pragma unroll
    for (int s = 0; s < 4; ++s) {
        const unsigned r = rbase + 256u * s;
        addr[s] = (r & 0x7Fu)
                | ((r & 0x1F80u)  << 1)
                | ((r & 0x1E000u) << 2)
                | ((r & 0xE0000u) << 3);
    }

    float acc[4][8];
    #pragma unroll
    for (int s = 0; s < 4; ++s)
        #pragma unroll
        for (int o = 0; o < 8; ++o) acc[s][o] = 0.f;

    #pragma unroll
    for (int i = 0; i < 8; ++i) {
        const float4* uv = (const float4*)&uL[(i * 8 + b) * 20];
        const float4 u01 = uv[0];   // (Ure[0],Uim[0],Ure[1],Uim[1])
        const float4 u23 = uv[1];
        const float4 u45 = uv[2];
        const float4 u67 = uv[3];
        const unsigned so = SUP_OFF(i);
        #pragma unroll
        for (int s = 0; s < 4; ++s) {
            const unsigned off = addr[s] + so;
            const float xr = sre_g[off];
            const float xi = sim_g[off];
            acc[s][0] += u01.x * xr - u01.y * xi;
            acc[s][1] += u01.z * xr - u01.w * xi;
            acc[s][2] += u23.x * xr - u23.y * xi;
            acc[s][3] += u23.z * xr - u23.w * xi;
            acc[s][4] += u45.x * xr - u45.y * xi;
            acc[s][5] += u45.z * xr - u45.w * xi;
            acc[s][6] += u67.x * xr - u67.y * xi;
            acc[s][7] += u67.z * xr - u67.w * xi;
        }
    }

    #pragma unroll
    for (int o = 0; o < 8; ++o) {
        const unsigned so = SUP_OFF(o);
        #pragma unroll
        for (int s = 0; s < 4; ++s) {
            out[addr[s] + so] = acc[s][o];
        }
    }
}

extern "C" void kernel_launch(void* const* d_in, const int* in_sizes, int n_in,
                              void* d_out, int out_size, void* d_ws, size_t ws_size,
                              hipStream_t stream) {
    const float* state_real = (const float*)d_in[0];
    const float* state_imag = (const float*)d_in[1];
    const float* h_real     = (const float*)d_in[2];
    const float* h_imag     = (const float*)d_in[3];
    const float* t          = (const float*)d_in[4];

    float* U = (float*)d_ws;   // 1024 floats = 4 KB

    expm_kernel<<<8, 64, 0, stream>>>(h_real, h_imag, t, U);

    // 2^20 elements / 4 per thread / 256 per block = 1024 blocks
    apply_kernel<<<1024, 256, 0, stream>>>(state_real, state_imag,
                                           (const float4*)U, (float*)d_out);
}

// Round 8
// 26.372 us; speedup vs baseline: 1.2276x; 1.0649x over previous
//
#include <hip/hip_runtime.h>

// PyQHamiltonianEvolution: N_QUBITS=20, SUPPORT=(3,8,15), BATCH=8, DIM=8
// state layout (2,)*20 + (8,) row-major, batch innermost.
// element-address support bits: q3 -> bit19 (524288), q8 -> bit14 (16384),
// q15 -> bit7 (128); batch = bits 0-2. Output = f32 REAL part, 2^23 elems.
//
// Kernel A: expm, 8 blocks x 64 threads (one wave per batch).
//           U stored to d_ws as float[1024]: [(i*8+b)*16 + 2o] = re, +1 = im.
// Kernel B: accumulate-over-i apply, 2 elements/thread, 2048 blocks
//           (8 blocks/CU -> 32 waves/CU theoretical). Per i-PAIR: 8 global
//           loads issued before any consumption (MLP), U columns from LDS
//           (broadcast, conflict-free stride-20 pad). Real-part accs only.

#define SUP_OFF(m) ( ((m)&4 ? 524288u : 0u) + ((m)&2 ? 16384u : 0u) + ((m)&1 ? 128u : 0u) )

__global__ void expm_kernel(const float* __restrict__ h_real,
                            const float* __restrict__ h_imag,
                            const float* __restrict__ t_g,
                            float* __restrict__ U)     // [ (i*8+b)*16 + 2o (+1) ]
{
    __shared__ float Tre[64], Tim[64], Mre[64], Mim[64], Ere[64], Eim[64];

    const int b = blockIdx.x;          // batch
    const int e = threadIdx.x;         // matrix entry, one per lane
    const int o = e >> 3, i = e & 7;

    const float sc  = t_g[b] * (1.0f / 32.0f);   // M = (-i t H) / 2^5
    const float mre =  sc * h_imag[e];
    const float mim = -sc * h_real[e];

    Mre[e] = mre; Mim[e] = mim;
    Tre[e] = mre; Tim[e] = mim;
    float are = (o == i ? 1.f : 0.f) + mre;      // E = I + M
    float aim = mim;
    __syncthreads();

    for (int k = 2; k <= 10; ++k) {    // T = T*M/k ; E += T
        float sre = 0.f, sim = 0.f;
        #pragma unroll
        for (int j = 0; j < 8; ++j) {
            const float tre = Tre[o * 8 + j], tim = Tim[o * 8 + j];
            const float qre = Mre[j * 8 + i], qim = Mim[j * 8 + i];
            sre += tre * qre - tim * qim;
            sim += tre * qim + tim * qre;
        }
        const float inv = 1.0f / (float)k;
        sre *= inv; sim *= inv;
        __syncthreads();
        Tre[e] = sre; Tim[e] = sim;
        are += sre; aim += sim;
        __syncthreads();
    }

    Ere[e] = are; Eim[e] = aim;
    __syncthreads();

    for (int sq = 0; sq < 5; ++sq) {   // E = E*E
        float sre = 0.f, sim = 0.f;
        #pragma unroll
        for (int j = 0; j < 8; ++j) {
            const float xre = Ere[o * 8 + j], xim = Eim[o * 8 + j];
            const float yre = Ere[j * 8 + i], yim = Eim[j * 8 + i];
            sre += xre * yre - xim * yim;
            sim += xre * yim + xim * yre;
        }
        __syncthreads();
        if (sq < 4) {
            Ere[e] = sre; Eim[e] = sim;
            __syncthreads();
        } else {
            U[(i * 8 + b) * 16 + 2 * o]     = sre;   // column-major for apply
            U[(i * 8 + b) * 16 + 2 * o + 1] = sim;
        }
    }
}

__global__ __launch_bounds__(256, 8) void apply_kernel(
        const float* __restrict__ sre_g,
        const float* __restrict__ sim_g,
        const float4* __restrict__ U4,   // 256 float4 = [i][b][16 floats]
        float* __restrict__ out)
{
    // LDS: [i][b] slots, stride 20 floats (banks b*20 mod 32 all distinct ->
    // conflict-free 8-address broadcast reads, 16B-aligned).
    __shared__ alignas(16) float uL[8 * 8 * 20];
    const int tid = threadIdx.x;
    {
        const float4 u = U4[tid];            // tid = (i*8+b)*4 + k
        const int ib = tid >> 2, k = tid & 3;
        *(float4*)&uL[ib * 20 + k * 4] = u;
    }
    __syncthreads();

    const unsigned rbase = blockIdx.x * 512u + tid;   // block owns 512 r
    const int b = tid & 7;                            // same b for both sets

    unsigned addr[2];
    #pragma unroll
    for (int s = 0; s < 2; ++s) {
        const unsigned r = rbase + 256u * s;
        addr[s] = (r & 0x7Fu)
                | ((r & 0x1F80u)  << 1)
                | ((r & 0x1E000u) << 2)
                | ((r & 0xE0000u) << 3);
    }

    float acc[2][8];
    #pragma unroll
    for (int s = 0; s < 2; ++s)
        #pragma unroll
        for (int o = 0; o < 8; ++o) acc[s][o] = 0.f;

    // i-pairs: issue all 8 loads for (i, i+1) x (s=0,1) x (re,im), then consume.
    #pragma unroll
    for (int ip = 0; ip < 4; ++ip) {
        const int ia = 2 * ip, ibb = 2 * ip + 1;
        const unsigned soa = SUP_OFF(ia), sob = SUP_OFF(ibb);

        const float xr0a = sre_g[addr[0] + soa];
        const float xi0a = sim_g[addr[0] + soa];
        const float xr1a = sre_g[addr[1] + soa];
        const float xi1a = sim_g[addr[1] + soa];
        const float xr0b = sre_g[addr[0] + sob];
        const float xi0b = sim_g[addr[0] + sob];
        const float xr1b = sre_g[addr[1] + sob];
        const float xi1b = sim_g[addr[1] + sob];

        {
            const float4* uv = (const float4*)&uL[(ia * 8 + b) * 20];
            const float4 u01 = uv[0], u23 = uv[1], u45 = uv[2], u67 = uv[3];
            acc[0][0] += u01.x * xr0a - u01.y * xi0a;
            acc[0][1] += u01.z * xr0a - u01.w * xi0a;
            acc[0][2] += u23.x * xr0a - u23.y * xi0a;
            acc[0][3] += u23.z * xr0a - u23.w * xi0a;
            acc[0][4] += u45.x * xr0a - u45.y * xi0a;
            acc[0][5] += u45.z * xr0a - u45.w * xi0a;
            acc[0][6] += u67.x * xr0a - u67.y * xi0a;
            acc[0][7] += u67.z * xr0a - u67.w * xi0a;
            acc[1][0] += u01.x * xr1a - u01.y * xi1a;
            acc[1][1] += u01.z * xr1a - u01.w * xi1a;
            acc[1][2] += u23.x * xr1a - u23.y * xi1a;
            acc[1][3] += u23.z * xr1a - u23.w * xi1a;
            acc[1][4] += u45.x * xr1a - u45.y * xi1a;
            acc[1][5] += u45.z * xr1a - u45.w * xi1a;
            acc[1][6] += u67.x * xr1a - u67.y * xi1a;
            acc[1][7] += u67.z * xr1a - u67.w * xi1a;
        }
        {
            const float4* uv = (const float4*)&uL[(ibb * 8 + b) * 20];
            const float4 u01 = uv[0], u23 = uv[1], u45 = uv[2], u67 = uv[3];
            acc[0][0] += u01.x * xr0b - u01.y * xi0b;
            acc[0][1] += u01.z * xr0b - u01.w * xi0b;
            acc[0][2] += u23.x * xr0b - u23.y * xi0b;
            acc[0][3] += u23.z * xr0b - u23.w * xi0b;
            acc[0][4] += u45.x * xr0b - u45.y * xi0b;
            acc[0][5] += u45.z * xr0b - u45.w * xi0b;
            acc[0][6] += u67.x * xr0b - u67.y * xi0b;
            acc[0][7] += u67.z * xr0b - u67.w * xi0b;
            acc[1][0] += u01.x * xr1b - u01.y * xi1b;
            acc[1][1] += u01.z * xr1b - u01.w * xi1b;
            acc[1][2] += u23.x * xr1b - u23.y * xi1b;
            acc[1][3] += u23.z * xr1b - u23.w * xi1b;
            acc[1][4] += u45.x * xr1b - u45.y * xi1b;
            acc[1][5] += u45.z * xr1b - u45.w * xi1b;
            acc[1][6] += u67.x * xr1b - u67.y * xi1b;
            acc[1][7] += u67.z * xr1b - u67.w * xi1b;
        }
    }

    #pragma unroll
    for (int o = 0; o < 8; ++o) {
        const unsigned so = SUP_OFF(o);
        out[addr[0] + so] = acc[0][o];
        out[addr[1] + so] = acc[1][o];
    }
}

extern "C" void kernel_launch(void* const* d_in, const int* in_sizes, int n_in,
                              void* d_out, int out_size, void* d_ws, size_t ws_size,
                              hipStream_t stream) {
    const float* state_real = (const float*)d_in[0];
    const float* state_imag = (const float*)d_in[1];
    const float* h_real     = (const float*)d_in[2];
    const float* h_imag     = (const float*)d_in[3];
    const float* t          = (const float*)d_in[4];

    float* U = (float*)d_ws;   // 1024 floats = 4 KB

    expm_kernel<<<8, 64, 0, stream>>>(h_real, h_imag, t, U);

    // 2^20 elements / 2 per thread / 256 per block = 2048 blocks
    apply_kernel<<<2048, 256, 0, stream>>>(state_real, state_imag,
                                           (const float4*)U, (float*)d_out);
}